// Round 6
// baseline (456.584 us; speedup 1.0000x reference)
//
#include <hip/hip_runtime.h>
#include <hip/hip_bf16.h>
#include <hip/hip_fp16.h>

#define N_NODES   100000
#define N_EDGES   1000000
#define HID       64
#define NUM_GRAPHS 1024
#define NREP      8    // outsum atomic replicas
#define CAP       64   // max in-degree bucket capacity (Poisson(10): P(>63) ~ 1e-35)

typedef _Float16 h16;

static __device__ __forceinline__ int pack2(float a, float b) {
    union { h16 h[2]; int i; } u;
    u.h[0] = (h16)a; u.h[1] = (h16)b;
    return u.i;
}
static __device__ __forceinline__ float uni_f(float x) {
    return __int_as_float(__builtin_amdgcn_readfirstlane(__float_as_int(x)));
}

// ---------------- graph build: fixed-stride bucket fill ----------------

__global__ __launch_bounds__(256) void bucket_fill(const int* __restrict__ src,
                                                   const int* __restrict__ dst,
                                                   int* __restrict__ cnt,
                                                   int* __restrict__ ebuf) {
    int e = blockIdx.x * 256 + threadIdx.x;
    if (e >= N_EDGES) return;
    int d = dst[e];
    int p = atomicAdd(&cnt[d], 1);
    if (p < CAP) ebuf[(size_t)d * CAP + p] = src[e];
}

// ---------------- xw = X @ W1, fp16 out, fused node_prep ----------------
// X tile staged via LDS: global loads fully coalesced (float4, lane-contiguous),
// per-thread row reads from LDS (stride 68 floats: 16B-aligned, 8-way banked).

__global__ __launch_bounds__(256) void gemm64h(const float* __restrict__ X,
                                               const float* __restrict__ W,
                                               const int* __restrict__ cnt,
                                               float* __restrict__ dinv,
                                               float* __restrict__ invd,
                                               h16* __restrict__ Y, int nrows) {
    __shared__ float Wl[4096];
    __shared__ float Xs[256 * 68];
    int t = threadIdx.x;
    #pragma unroll
    for (int i = 0; i < 4; i++) {
        int idx = (t + i * 256) * 4;
        *(float4*)(Wl + idx) = *(const float4*)(W + idx);
    }
    // stage 256 rows (4096 float4) coalesced
    const float4* Xg = (const float4*)X + (size_t)blockIdx.x * 4096;
    int maxf4 = nrows * 16 - blockIdx.x * 4096;
    #pragma unroll
    for (int i = 0; i < 16; i++) {
        int f = t + i * 256;
        if (f < maxf4) {
            float4 v = Xg[f];
            int r = f >> 4, c = f & 15;
            *(float4*)&Xs[r * 68 + c * 4] = v;
        }
    }
    __syncthreads();
    int row = blockIdx.x * 256 + t;
    if (row >= nrows) return;

    // fused node_prep
    float df = (float)(min(cnt[row], CAP) + 1);   // +1 self loop
    dinv[row] = rsqrtf(df);
    invd[row] = 1.0f / df;

    const float* xr = Xs + t * 68;
    float4 acc[16];
    #pragma unroll
    for (int j = 0; j < 16; j++) acc[j] = make_float4(0.f, 0.f, 0.f, 0.f);
    #pragma unroll
    for (int k4 = 0; k4 < 16; k4++) {
        float4 xv = *(const float4*)(xr + k4 * 4);
        #pragma unroll
        for (int kk = 0; kk < 4; kk++) {
            float xk = (kk == 0) ? xv.x : (kk == 1) ? xv.y : (kk == 2) ? xv.z : xv.w;
            const float4* wr = (const float4*)(Wl + (k4 * 4 + kk) * 64);
            #pragma unroll
            for (int j = 0; j < 16; j++) {
                float4 w = wr[j];   // LDS broadcast
                acc[j].x += xk * w.x;
                acc[j].y += xk * w.y;
                acc[j].z += xk * w.z;
                acc[j].w += xk * w.w;
            }
        }
    }
    int4* yr = (int4*)(Y + (size_t)row * 64);
    #pragma unroll
    for (int j = 0; j < 8; j++) {
        float4 a = acc[2 * j], b = acc[2 * j + 1];
        int4 o;
        o.x = pack2(a.x, a.y); o.y = pack2(a.z, a.w);
        o.z = pack2(b.x, b.y); o.w = pack2(b.z, b.w);
        yr[j] = o;
    }
}

// ---------------- aggregation: one wave per node, lane = channel ----------------
// Edge list (<=64) loaded in ONE lane-parallel load; per-edge (src,norm)
// broadcast via v_readlane. Gathers batched in unmasked chunks (16 + binary
// tail 8/4/2/1) -> exactly deg loads, high MLP, no padding waste.

template <int U>
static __device__ __forceinline__ float agg_chunk(const h16* __restrict__ XW,
                                                  int es, float nv, int j, int lane) {
    int   ss[U]; float nn[U], vv[U];
    #pragma unroll
    for (int u = 0; u < U; u++) {
        ss[u] = __builtin_amdgcn_readlane(es, j + u);
        nn[u] = __int_as_float(__builtin_amdgcn_readlane(__float_as_int(nv), j + u));
    }
    #pragma unroll
    for (int u = 0; u < U; u++)
        vv[u] = (float)XW[(((unsigned)ss[u]) << 6) | (unsigned)lane];
    float a = 0.f;
    #pragma unroll
    for (int u = 0; u < U; u++) a = fmaf(vv[u], nn[u], a);
    return a;
}

static __device__ __forceinline__ float agg_edges(const h16* __restrict__ XW,
                                                  const int* __restrict__ ebuf,
                                                  const float* __restrict__ dinv,
                                                  int wid, int deg, float dvw, int lane) {
    if (deg <= 0) return 0.f;
    int es = ebuf[wid * CAP + (lane < deg ? lane : deg - 1)];
    float nv = dinv[es] * dvw;   // per-lane 4B gather, L2-resident
    float acc = 0.f;
    int j = 0;
    for (; j + 16 <= deg; j += 16) { acc += agg_chunk<16>(XW, es, nv, j, lane); }
    if (deg & 8) { acc += agg_chunk<8>(XW, es, nv, j, lane); j += 8; }
    if (deg & 4) { acc += agg_chunk<4>(XW, es, nv, j, lane); j += 4; }
    if (deg & 2) { acc += agg_chunk<2>(XW, es, nv, j, lane); j += 2; }
    if (deg & 1) { acc += agg_chunk<1>(XW, es, nv, j, lane); }
    return acc;
}

// layer-1 aggregation + bias + ReLU + fused (h @ W2) -> Y2 (fp16)
__global__ __launch_bounds__(256) void agg_gemm_relu(const h16* __restrict__ XW,
                                                     const int* __restrict__ cnt,
                                                     const int* __restrict__ ebuf,
                                                     const float* __restrict__ dinv,
                                                     const float* __restrict__ invd,
                                                     const float* __restrict__ bias,
                                                     const float* __restrict__ W2,
                                                     h16* __restrict__ Y2) {
    __shared__ float W2l[4096];
    int t = threadIdx.x;
    #pragma unroll
    for (int i = 0; i < 4; i++) {
        int idx = (t + i * 256) * 4;
        *(float4*)(W2l + idx) = *(const float4*)(W2 + idx);
    }
    __syncthreads();

    int lane = t & 63;
    int wid = __builtin_amdgcn_readfirstlane(blockIdx.x * 4 + (t >> 6));
    if (wid >= N_NODES) return;
    int deg = min(__builtin_amdgcn_readfirstlane(cnt[wid]), CAP);
    float dvw = uni_f(dinv[wid]);
    float sw  = uni_f(invd[wid]);
    float acc = (float)XW[(((unsigned)wid) << 6) | (unsigned)lane] * sw;
    acc += agg_edges(XW, ebuf, dinv, wid, deg, dvw, lane);
    float h = fmaxf(acc + bias[lane], 0.f);

    // y[lane] = sum_k h[k] * W2[k][lane]
    float y = 0.f;
    #pragma unroll
    for (int k = 0; k < 64; k++) {
        float hk = __int_as_float(__builtin_amdgcn_readlane(__float_as_int(h), k));
        y = fmaf(hk, W2l[k * 64 + lane], y);
    }
    Y2[(((unsigned)wid) << 6) | (unsigned)lane] = (h16)y;
}

// layer-2 aggregation + ReLU + dot(Wout) + per-graph accumulation
__global__ __launch_bounds__(256) void agg_pool(const h16* __restrict__ XW,
                                                const int* __restrict__ cnt,
                                                const int* __restrict__ ebuf,
                                                const float* __restrict__ dinv,
                                                const float* __restrict__ invd,
                                                const float* __restrict__ bias,
                                                const float* __restrict__ Wout,
                                                const int* __restrict__ batch,
                                                float* __restrict__ outsum) {
    int lane = threadIdx.x & 63;
    int wid = __builtin_amdgcn_readfirstlane(blockIdx.x * 4 + (threadIdx.x >> 6));
    if (wid >= N_NODES) return;
    int deg = min(__builtin_amdgcn_readfirstlane(cnt[wid]), CAP);
    float dvw = uni_f(dinv[wid]);
    float sw  = uni_f(invd[wid]);
    float acc = (float)XW[(((unsigned)wid) << 6) | (unsigned)lane] * sw;
    acc += agg_edges(XW, ebuf, dinv, wid, deg, dvw, lane);
    float h = fmaxf(acc + bias[lane], 0.f);
    float v = h * Wout[lane];
    #pragma unroll
    for (int off = 32; off > 0; off >>= 1) v += __shfl_down(v, off, 64);
    if (lane == 0) {
        int g = batch[wid];
        atomicAdd(&outsum[(wid & (NREP - 1)) * NUM_GRAPHS + g], v);
    }
}

__global__ __launch_bounds__(256) void finalize(const float* __restrict__ outsum,
                                                const int* __restrict__ batch,
                                                const float* __restrict__ bout,
                                                float* __restrict__ out) {
    int g = blockIdx.x * 256 + threadIdx.x;
    if (g >= NUM_GRAPHS) return;
    float s = 0.f;
    #pragma unroll
    for (int r = 0; r < NREP; r++) s += outsum[r * NUM_GRAPHS + g];
    int lo = 0, hi = N_NODES;
    while (lo < hi) { int mid = (lo + hi) >> 1; if (batch[mid] <  g) lo = mid + 1; else hi = mid; }
    int lo2 = lo, hi2 = N_NODES;
    while (lo2 < hi2) { int mid = (lo2 + hi2) >> 1; if (batch[mid] <= g) lo2 = mid + 1; else hi2 = mid; }
    float c = (float)max(lo2 - lo, 1);
    out[g] = s / c + bout[0];
}

// ---------------- launch ----------------

extern "C" void kernel_launch(void* const* d_in, const int* in_sizes, int n_in,
                              void* d_out, int out_size, void* d_ws, size_t ws_size,
                              hipStream_t stream) {
    const float* x     = (const float*)d_in[0];
    const int*   eidx  = (const int*)d_in[1];   // [2, E]
    const int*   batch = (const int*)d_in[2];
    const float* W1    = (const float*)d_in[3];
    const float* b1    = (const float*)d_in[4];
    const float* W2    = (const float*)d_in[5];
    const float* b2    = (const float*)d_in[6];
    const float* Wout  = (const float*)d_in[7];
    const float* bout  = (const float*)d_in[8];
    float* out = (float*)d_out;

    const int* src = eidx;
    const int* dst = eidx + N_EDGES;

    // workspace layout
    h16*   xw     = (h16*)d_ws;                         // 12.8 MB
    h16*   y2     = xw + (size_t)N_NODES * 64;          // 12.8 MB
    int*   ebuf   = (int*)(y2 + (size_t)N_NODES * 64);  // 25.6 MB
    int*   cnt    = ebuf + (size_t)N_NODES * CAP;       // 400 KB
    float* outsum = (float*)(cnt + N_NODES);            // 32 KB
    float* dinv   = outsum + NREP * NUM_GRAPHS;         // 400 KB
    float* invd   = dinv + N_NODES;                     // 400 KB

    // zero cnt + outsum (contiguous)
    hipMemsetAsync(cnt, 0, (size_t)(N_NODES + NREP * NUM_GRAPHS) * sizeof(int), stream);

    const int EB = (N_EDGES + 255) / 256;
    const int NB = (N_NODES + 255) / 256;
    const int AB = (N_NODES + 3) / 4;       // 4 nodes (waves) per block

    bucket_fill<<<EB, 256, 0, stream>>>(src, dst, cnt, ebuf);
    gemm64h<<<NB, 256, 0, stream>>>(x, W1, cnt, dinv, invd, xw, N_NODES);
    agg_gemm_relu<<<AB, 256, 0, stream>>>(xw, cnt, ebuf, dinv, invd, b1, W2, y2);
    agg_pool<<<AB, 256, 0, stream>>>(y2, cnt, ebuf, dinv, invd, b2, Wout, batch, outsum);
    finalize<<<(NUM_GRAPHS + 255) / 256, 256, 0, stream>>>(outsum, batch, bout, out);
}

// Round 7
// 292.592 us; speedup vs baseline: 1.5605x; 1.5605x over previous
//
#include <hip/hip_runtime.h>
#include <hip/hip_bf16.h>
#include <hip/hip_fp16.h>

#define N_NODES   100000
#define N_EDGES   1000000
#define HID       64
#define NUM_GRAPHS 1024
#define NREP      8    // outsum atomic replicas
#define CAP       64   // max in-degree bucket capacity (Poisson(10): P(>63) ~ 1e-35)

typedef _Float16 h16;

static __device__ __forceinline__ int pack2(float a, float b) {
    union { h16 h[2]; int i; } u;
    u.h[0] = (h16)a; u.h[1] = (h16)b;
    return u.i;
}
static __device__ __forceinline__ float uni_f(float x) {
    return __int_as_float(__builtin_amdgcn_readfirstlane(__float_as_int(x)));
}

// ---------------- graph build: fixed-stride bucket fill ----------------

__global__ __launch_bounds__(256) void bucket_fill(const int* __restrict__ src,
                                                   const int* __restrict__ dst,
                                                   int* __restrict__ cnt,
                                                   int* __restrict__ ebuf) {
    int e = blockIdx.x * 256 + threadIdx.x;
    if (e >= N_EDGES) return;
    int d = dst[e];
    int p = atomicAdd(&cnt[d], 1);
    if (p < CAP) ebuf[(size_t)d * CAP + p] = src[e];
}

// ---------------- xw = X @ W1, fp16 out, fused node_prep ----------------
// 2 threads per row (32 channels each): acc=32 VGPR, 782 blocks, adjacent
// lane-pairs share X cache lines. W broadcast from 16KB LDS (2-addr b128,
// 2-way groups = conflict-free). No X staging tile (R6's 86KB LDS was a
// 1-block/CU occupancy cliff).

__global__ __launch_bounds__(256) void gemm64h(const float* __restrict__ X,
                                               const float* __restrict__ W,
                                               const int* __restrict__ cnt,
                                               float* __restrict__ dinv,
                                               float* __restrict__ invd,
                                               h16* __restrict__ Y, int nrows) {
    __shared__ float Wl[4096];
    int t = threadIdx.x;
    #pragma unroll
    for (int i = 0; i < 4; i++) {
        int idx = (t + i * 256) * 4;
        *(float4*)(Wl + idx) = *(const float4*)(W + idx);
    }
    __syncthreads();
    int row  = blockIdx.x * 128 + (t >> 1);
    if (row >= nrows) return;
    int half = t & 1;   // which 32 channels

    if (half == 0) {   // fused node_prep (one thread per row)
        float df = (float)(min(cnt[row], CAP) + 1);   // +1 self loop
        dinv[row] = rsqrtf(df);
        invd[row] = 1.0f / df;
    }

    const float4* xr = (const float4*)(X + (size_t)row * 64);
    float4 acc[8];
    #pragma unroll
    for (int j = 0; j < 8; j++) acc[j] = make_float4(0.f, 0.f, 0.f, 0.f);
    const float* wb = Wl + half * 32;
    #pragma unroll
    for (int k4 = 0; k4 < 16; k4++) {
        float4 xv = xr[k4];
        #pragma unroll
        for (int kk = 0; kk < 4; kk++) {
            float xk = (kk == 0) ? xv.x : (kk == 1) ? xv.y : (kk == 2) ? xv.z : xv.w;
            const float4* wr = (const float4*)(wb + (k4 * 4 + kk) * 64);
            #pragma unroll
            for (int j = 0; j < 8; j++) {
                float4 w = wr[j];
                acc[j].x += xk * w.x;
                acc[j].y += xk * w.y;
                acc[j].z += xk * w.z;
                acc[j].w += xk * w.w;
            }
        }
    }
    int4* yr = (int4*)(Y + (size_t)row * 64 + half * 32);
    #pragma unroll
    for (int j = 0; j < 4; j++) {
        float4 a = acc[2 * j], b = acc[2 * j + 1];
        int4 o;
        o.x = pack2(a.x, a.y); o.y = pack2(a.z, a.w);
        o.z = pack2(b.x, b.y); o.w = pack2(b.z, b.w);
        yr[j] = o;
    }
}

// ---------------- aggregation: one wave per node, lane = channel ----------------
// Edge list (<=64) loaded in ONE lane-parallel load; per-edge (src,norm)
// broadcast via v_readlane. Gathers batched in unmasked chunks (16 + binary
// tail 8/4/2/1) -> exactly deg loads, high MLP, no padding waste.

template <int U>
static __device__ __forceinline__ float agg_chunk(const h16* __restrict__ XW,
                                                  int es, float nv, int j, int lane) {
    int   ss[U]; float nn[U], vv[U];
    #pragma unroll
    for (int u = 0; u < U; u++) {
        ss[u] = __builtin_amdgcn_readlane(es, j + u);
        nn[u] = __int_as_float(__builtin_amdgcn_readlane(__float_as_int(nv), j + u));
    }
    #pragma unroll
    for (int u = 0; u < U; u++)
        vv[u] = (float)XW[(((unsigned)ss[u]) << 6) | (unsigned)lane];
    float a = 0.f;
    #pragma unroll
    for (int u = 0; u < U; u++) a = fmaf(vv[u], nn[u], a);
    return a;
}

static __device__ __forceinline__ float agg_edges(const h16* __restrict__ XW,
                                                  const int* __restrict__ ebuf,
                                                  const float* __restrict__ dinv,
                                                  int wid, int deg, float dvw, int lane) {
    if (deg <= 0) return 0.f;
    int es = ebuf[wid * CAP + (lane < deg ? lane : deg - 1)];
    float nv = dinv[es] * dvw;   // per-lane 4B gather, L2-resident
    float acc = 0.f;
    int j = 0;
    for (; j + 16 <= deg; j += 16) { acc += agg_chunk<16>(XW, es, nv, j, lane); }
    if (deg & 8) { acc += agg_chunk<8>(XW, es, nv, j, lane); j += 8; }
    if (deg & 4) { acc += agg_chunk<4>(XW, es, nv, j, lane); j += 4; }
    if (deg & 2) { acc += agg_chunk<2>(XW, es, nv, j, lane); j += 2; }
    if (deg & 1) { acc += agg_chunk<1>(XW, es, nv, j, lane); }
    return acc;
}

// layer-1 aggregation + bias + ReLU + fused (h @ W2) -> Y2 (fp16)
__global__ __launch_bounds__(256) void agg_gemm_relu(const h16* __restrict__ XW,
                                                     const int* __restrict__ cnt,
                                                     const int* __restrict__ ebuf,
                                                     const float* __restrict__ dinv,
                                                     const float* __restrict__ invd,
                                                     const float* __restrict__ bias,
                                                     const float* __restrict__ W2,
                                                     h16* __restrict__ Y2) {
    __shared__ float W2l[4096];
    int t = threadIdx.x;
    #pragma unroll
    for (int i = 0; i < 4; i++) {
        int idx = (t + i * 256) * 4;
        *(float4*)(W2l + idx) = *(const float4*)(W2 + idx);
    }
    __syncthreads();

    int lane = t & 63;
    int wid = __builtin_amdgcn_readfirstlane(blockIdx.x * 4 + (t >> 6));
    if (wid >= N_NODES) return;
    int deg = min(__builtin_amdgcn_readfirstlane(cnt[wid]), CAP);
    float dvw = uni_f(dinv[wid]);
    float sw  = uni_f(invd[wid]);
    float acc = (float)XW[(((unsigned)wid) << 6) | (unsigned)lane] * sw;
    acc += agg_edges(XW, ebuf, dinv, wid, deg, dvw, lane);
    float h = fmaxf(acc + bias[lane], 0.f);

    // y[lane] = sum_k h[k] * W2[k][lane]
    float y = 0.f;
    #pragma unroll
    for (int k = 0; k < 64; k++) {
        float hk = __int_as_float(__builtin_amdgcn_readlane(__float_as_int(h), k));
        y = fmaf(hk, W2l[k * 64 + lane], y);
    }
    Y2[(((unsigned)wid) << 6) | (unsigned)lane] = (h16)y;
}

// layer-2 aggregation + ReLU + dot(Wout) + per-graph accumulation
__global__ __launch_bounds__(256) void agg_pool(const h16* __restrict__ XW,
                                                const int* __restrict__ cnt,
                                                const int* __restrict__ ebuf,
                                                const float* __restrict__ dinv,
                                                const float* __restrict__ invd,
                                                const float* __restrict__ bias,
                                                const float* __restrict__ Wout,
                                                const int* __restrict__ batch,
                                                float* __restrict__ outsum) {
    int lane = threadIdx.x & 63;
    int wid = __builtin_amdgcn_readfirstlane(blockIdx.x * 4 + (threadIdx.x >> 6));
    if (wid >= N_NODES) return;
    int deg = min(__builtin_amdgcn_readfirstlane(cnt[wid]), CAP);
    float dvw = uni_f(dinv[wid]);
    float sw  = uni_f(invd[wid]);
    float acc = (float)XW[(((unsigned)wid) << 6) | (unsigned)lane] * sw;
    acc += agg_edges(XW, ebuf, dinv, wid, deg, dvw, lane);
    float h = fmaxf(acc + bias[lane], 0.f);
    float v = h * Wout[lane];
    #pragma unroll
    for (int off = 32; off > 0; off >>= 1) v += __shfl_down(v, off, 64);
    if (lane == 0) {
        int g = batch[wid];
        atomicAdd(&outsum[(wid & (NREP - 1)) * NUM_GRAPHS + g], v);
    }
}

__global__ __launch_bounds__(256) void finalize(const float* __restrict__ outsum,
                                                const int* __restrict__ batch,
                                                const float* __restrict__ bout,
                                                float* __restrict__ out) {
    int g = blockIdx.x * 256 + threadIdx.x;
    if (g >= NUM_GRAPHS) return;
    float s = 0.f;
    #pragma unroll
    for (int r = 0; r < NREP; r++) s += outsum[r * NUM_GRAPHS + g];
    int lo = 0, hi = N_NODES;
    while (lo < hi) { int mid = (lo + hi) >> 1; if (batch[mid] <  g) lo = mid + 1; else hi = mid; }
    int lo2 = lo, hi2 = N_NODES;
    while (lo2 < hi2) { int mid = (lo2 + hi2) >> 1; if (batch[mid] <= g) lo2 = mid + 1; else hi2 = mid; }
    float c = (float)max(lo2 - lo, 1);
    out[g] = s / c + bout[0];
}

// ---------------- launch ----------------

extern "C" void kernel_launch(void* const* d_in, const int* in_sizes, int n_in,
                              void* d_out, int out_size, void* d_ws, size_t ws_size,
                              hipStream_t stream) {
    const float* x     = (const float*)d_in[0];
    const int*   eidx  = (const int*)d_in[1];   // [2, E]
    const int*   batch = (const int*)d_in[2];
    const float* W1    = (const float*)d_in[3];
    const float* b1    = (const float*)d_in[4];
    const float* W2    = (const float*)d_in[5];
    const float* b2    = (const float*)d_in[6];
    const float* Wout  = (const float*)d_in[7];
    const float* bout  = (const float*)d_in[8];
    float* out = (float*)d_out;

    const int* src = eidx;
    const int* dst = eidx + N_EDGES;

    // workspace layout
    h16*   xw     = (h16*)d_ws;                         // 12.8 MB
    h16*   y2     = xw + (size_t)N_NODES * 64;          // 12.8 MB
    int*   ebuf   = (int*)(y2 + (size_t)N_NODES * 64);  // 25.6 MB
    int*   cnt    = ebuf + (size_t)N_NODES * CAP;       // 400 KB
    float* outsum = (float*)(cnt + N_NODES);            // 32 KB
    float* dinv   = outsum + NREP * NUM_GRAPHS;         // 400 KB
    float* invd   = dinv + N_NODES;                     // 400 KB

    // zero cnt + outsum (contiguous)
    hipMemsetAsync(cnt, 0, (size_t)(N_NODES + NREP * NUM_GRAPHS) * sizeof(int), stream);

    const int EB = (N_EDGES + 255) / 256;
    const int GB = (N_NODES + 127) / 128;   // 2 threads per row
    const int AB = (N_NODES + 3) / 4;       // 4 nodes (waves) per block

    bucket_fill<<<EB, 256, 0, stream>>>(src, dst, cnt, ebuf);
    gemm64h<<<GB, 256, 0, stream>>>(x, W1, cnt, dinv, invd, xw, N_NODES);
    agg_gemm_relu<<<AB, 256, 0, stream>>>(xw, cnt, ebuf, dinv, invd, b1, W2, y2);
    agg_pool<<<AB, 256, 0, stream>>>(y2, cnt, ebuf, dinv, invd, b2, Wout, batch, outsum);
    finalize<<<(NUM_GRAPHS + 255) / 256, 256, 0, stream>>>(outsum, batch, bout, out);
}

// Round 8
// 275.555 us; speedup vs baseline: 1.6570x; 1.0618x over previous
//
#include <hip/hip_runtime.h>
#include <hip/hip_bf16.h>
#include <hip/hip_fp16.h>

#define N_NODES   100000
#define N_EDGES   1000000
#define HID       64
#define NUM_GRAPHS 1024
#define NREP      8    // outsum atomic replicas
#define CAP       64   // max in-degree bucket capacity (Poisson(10): max deg ~30)

typedef _Float16 h16;

static __device__ __forceinline__ int pack2(float a, float b) {
    union { h16 h[2]; int i; } u;
    u.h[0] = (h16)a; u.h[1] = (h16)b;
    return u.i;
}
static __device__ __forceinline__ float uni_f(float x) {
    return __int_as_float(__builtin_amdgcn_readfirstlane(__float_as_int(x)));
}

// ---------------- graph build: XCD-partitioned bucket fill ----------------
// Partition p owns dst granules where (d>>7)&7 == p (cnt and ebuf lines are
// partition-pure). blockIdx&7 ~ XCD id (HW round-robin heuristic): a
// partition's 3.2 MB write set stays in ONE XCD L2 -> lines evict once.
// dst re-read 8x but 7/8 of those hit Infinity Cache.

__global__ __launch_bounds__(256) void bucket_fill(const int* __restrict__ src,
                                                   const int* __restrict__ dst,
                                                   int* __restrict__ cnt,
                                                   int* __restrict__ ebuf) {
    int part  = blockIdx.x & 7;
    int e     = (blockIdx.x >> 3) * 256 + threadIdx.x;
    if (e >= N_EDGES) return;
    int d = dst[e];
    if (((d >> 7) & 7) != part) return;
    int p = atomicAdd(&cnt[d], 1);
    if (p < CAP) ebuf[(size_t)d * CAP + p] = src[e];
}

// ---------------- xw = X @ W1, fp16 out, fused node_prep ----------------
// 2 threads per row (32 channels each): acc=32 VGPR, 782 blocks, adjacent
// lane-pairs share X cache lines. W broadcast from 16KB LDS.

__global__ __launch_bounds__(256) void gemm64h(const float* __restrict__ X,
                                               const float* __restrict__ W,
                                               const int* __restrict__ cnt,
                                               float* __restrict__ dinv,
                                               float* __restrict__ invd,
                                               h16* __restrict__ Y, int nrows) {
    __shared__ float Wl[4096];
    int t = threadIdx.x;
    #pragma unroll
    for (int i = 0; i < 4; i++) {
        int idx = (t + i * 256) * 4;
        *(float4*)(Wl + idx) = *(const float4*)(W + idx);
    }
    __syncthreads();
    int row  = blockIdx.x * 128 + (t >> 1);
    if (row >= nrows) return;
    int half = t & 1;   // which 32 channels

    if (half == 0) {   // fused node_prep (one thread per row)
        float df = (float)(min(cnt[row], CAP) + 1);   // +1 self loop
        dinv[row] = rsqrtf(df);
        invd[row] = 1.0f / df;
    }

    const float4* xr = (const float4*)(X + (size_t)row * 64);
    float4 acc[8];
    #pragma unroll
    for (int j = 0; j < 8; j++) acc[j] = make_float4(0.f, 0.f, 0.f, 0.f);
    const float* wb = Wl + half * 32;
    #pragma unroll
    for (int k4 = 0; k4 < 16; k4++) {
        float4 xv = xr[k4];
        #pragma unroll
        for (int kk = 0; kk < 4; kk++) {
            float xk = (kk == 0) ? xv.x : (kk == 1) ? xv.y : (kk == 2) ? xv.z : xv.w;
            const float4* wr = (const float4*)(wb + (k4 * 4 + kk) * 64);
            #pragma unroll
            for (int j = 0; j < 8; j++) {
                float4 w = wr[j];
                acc[j].x += xk * w.x;
                acc[j].y += xk * w.y;
                acc[j].z += xk * w.z;
                acc[j].w += xk * w.w;
            }
        }
    }
    int4* yr = (int4*)(Y + (size_t)row * 64 + half * 32);
    #pragma unroll
    for (int j = 0; j < 4; j++) {
        float4 a = acc[2 * j], b = acc[2 * j + 1];
        int4 o;
        o.x = pack2(a.x, a.y); o.y = pack2(a.z, a.w);
        o.z = pack2(b.x, b.y); o.w = pack2(b.z, b.w);
        yr[j] = o;
    }
}

// ---------------- aggregation: one wave per node, lane = channel ----------------
// Edge list (<=64) loaded in ONE lane-parallel load; per-edge (src,norm)
// broadcast via v_readlane. Gathers batched in unmasked chunks (16 + binary
// tail 8/4/2/1) -> exactly deg loads, high MLP, no padding waste.

template <int U>
static __device__ __forceinline__ float agg_chunk(const h16* __restrict__ XW,
                                                  int es, float nv, int j, int lane) {
    int   ss[U]; float nn[U], vv[U];
    #pragma unroll
    for (int u = 0; u < U; u++) {
        ss[u] = __builtin_amdgcn_readlane(es, j + u);
        nn[u] = __int_as_float(__builtin_amdgcn_readlane(__float_as_int(nv), j + u));
    }
    #pragma unroll
    for (int u = 0; u < U; u++)
        vv[u] = (float)XW[(((unsigned)ss[u]) << 6) | (unsigned)lane];
    float a = 0.f;
    #pragma unroll
    for (int u = 0; u < U; u++) a = fmaf(vv[u], nn[u], a);
    return a;
}

static __device__ __forceinline__ float agg_edges(const h16* __restrict__ XW,
                                                  const int* __restrict__ ebuf,
                                                  const float* __restrict__ dinv,
                                                  int wid, int deg, float dvw, int lane) {
    if (deg <= 0) return 0.f;
    int es = ebuf[wid * CAP + (lane < deg ? lane : deg - 1)];
    float nv = dinv[es] * dvw;   // per-lane 4B gather, L2-resident
    float acc = 0.f;
    int j = 0;
    for (; j + 16 <= deg; j += 16) { acc += agg_chunk<16>(XW, es, nv, j, lane); }
    if (deg & 8) { acc += agg_chunk<8>(XW, es, nv, j, lane); j += 8; }
    if (deg & 4) { acc += agg_chunk<4>(XW, es, nv, j, lane); j += 4; }
    if (deg & 2) { acc += agg_chunk<2>(XW, es, nv, j, lane); j += 2; }
    if (deg & 1) { acc += agg_chunk<1>(XW, es, nv, j, lane); }
    return acc;
}

// layer-1 aggregation + bias + ReLU + fused (h @ W2) -> Y2 (fp16)
__global__ __launch_bounds__(256) void agg_gemm_relu(const h16* __restrict__ XW,
                                                     const int* __restrict__ cnt,
                                                     const int* __restrict__ ebuf,
                                                     const float* __restrict__ dinv,
                                                     const float* __restrict__ invd,
                                                     const float* __restrict__ bias,
                                                     const float* __restrict__ W2,
                                                     h16* __restrict__ Y2) {
    __shared__ float W2l[4096];
    int t = threadIdx.x;
    #pragma unroll
    for (int i = 0; i < 4; i++) {
        int idx = (t + i * 256) * 4;
        *(float4*)(W2l + idx) = *(const float4*)(W2 + idx);
    }
    __syncthreads();

    int lane = t & 63;
    int wid = __builtin_amdgcn_readfirstlane(blockIdx.x * 4 + (t >> 6));
    if (wid >= N_NODES) return;
    int deg = min(__builtin_amdgcn_readfirstlane(cnt[wid]), CAP);
    float dvw = uni_f(dinv[wid]);
    float sw  = uni_f(invd[wid]);
    float acc = (float)XW[(((unsigned)wid) << 6) | (unsigned)lane] * sw;
    acc += agg_edges(XW, ebuf, dinv, wid, deg, dvw, lane);
    float h = fmaxf(acc + bias[lane], 0.f);

    // y[lane] = sum_k h[k] * W2[k][lane]
    float y = 0.f;
    #pragma unroll
    for (int k = 0; k < 64; k++) {
        float hk = __int_as_float(__builtin_amdgcn_readlane(__float_as_int(h), k));
        y = fmaf(hk, W2l[k * 64 + lane], y);
    }
    Y2[(((unsigned)wid) << 6) | (unsigned)lane] = (h16)y;
}

// layer-2 aggregation + ReLU + dot(Wout) + per-graph accumulation
__global__ __launch_bounds__(256) void agg_pool(const h16* __restrict__ XW,
                                                const int* __restrict__ cnt,
                                                const int* __restrict__ ebuf,
                                                const float* __restrict__ dinv,
                                                const float* __restrict__ invd,
                                                const float* __restrict__ bias,
                                                const float* __restrict__ Wout,
                                                const int* __restrict__ batch,
                                                float* __restrict__ outsum) {
    int lane = threadIdx.x & 63;
    int wid = __builtin_amdgcn_readfirstlane(blockIdx.x * 4 + (threadIdx.x >> 6));
    if (wid >= N_NODES) return;
    int deg = min(__builtin_amdgcn_readfirstlane(cnt[wid]), CAP);
    float dvw = uni_f(dinv[wid]);
    float sw  = uni_f(invd[wid]);
    float acc = (float)XW[(((unsigned)wid) << 6) | (unsigned)lane] * sw;
    acc += agg_edges(XW, ebuf, dinv, wid, deg, dvw, lane);
    float h = fmaxf(acc + bias[lane], 0.f);
    float v = h * Wout[lane];
    #pragma unroll
    for (int off = 32; off > 0; off >>= 1) v += __shfl_down(v, off, 64);
    if (lane == 0) {
        int g = batch[wid];
        atomicAdd(&outsum[(wid & (NREP - 1)) * NUM_GRAPHS + g], v);
    }
}

__global__ __launch_bounds__(256) void finalize(const float* __restrict__ outsum,
                                                const int* __restrict__ batch,
                                                const float* __restrict__ bout,
                                                float* __restrict__ out) {
    int g = blockIdx.x * 256 + threadIdx.x;
    if (g >= NUM_GRAPHS) return;
    float s = 0.f;
    #pragma unroll
    for (int r = 0; r < NREP; r++) s += outsum[r * NUM_GRAPHS + g];
    int lo = 0, hi = N_NODES;
    while (lo < hi) { int mid = (lo + hi) >> 1; if (batch[mid] <  g) lo = mid + 1; else hi = mid; }
    int lo2 = lo, hi2 = N_NODES;
    while (lo2 < hi2) { int mid = (lo2 + hi2) >> 1; if (batch[mid] <= g) lo2 = mid + 1; else hi2 = mid; }
    float c = (float)max(lo2 - lo, 1);
    out[g] = s / c + bout[0];
}

// ---------------- launch ----------------

extern "C" void kernel_launch(void* const* d_in, const int* in_sizes, int n_in,
                              void* d_out, int out_size, void* d_ws, size_t ws_size,
                              hipStream_t stream) {
    const float* x     = (const float*)d_in[0];
    const int*   eidx  = (const int*)d_in[1];   // [2, E]
    const int*   batch = (const int*)d_in[2];
    const float* W1    = (const float*)d_in[3];
    const float* b1    = (const float*)d_in[4];
    const float* W2    = (const float*)d_in[5];
    const float* b2    = (const float*)d_in[6];
    const float* Wout  = (const float*)d_in[7];
    const float* bout  = (const float*)d_in[8];
    float* out = (float*)d_out;

    const int* src = eidx;
    const int* dst = eidx + N_EDGES;

    // workspace layout
    h16*   xw     = (h16*)d_ws;                         // 12.8 MB
    h16*   y2     = xw + (size_t)N_NODES * 64;          // 12.8 MB
    int*   ebuf   = (int*)(y2 + (size_t)N_NODES * 64);  // 25.6 MB
    int*   cnt    = ebuf + (size_t)N_NODES * CAP;       // 400 KB
    float* outsum = (float*)(cnt + N_NODES);            // 32 KB
    float* dinv   = outsum + NREP * NUM_GRAPHS;         // 400 KB
    float* invd   = dinv + N_NODES;                     // 400 KB

    // zero cnt + outsum (contiguous)
    hipMemsetAsync(cnt, 0, (size_t)(N_NODES + NREP * NUM_GRAPHS) * sizeof(int), stream);

    const int EB = (N_EDGES + 255) / 256;
    const int GB = (N_NODES + 127) / 128;   // 2 threads per row
    const int AB = (N_NODES + 3) / 4;       // 4 nodes (waves) per block

    bucket_fill<<<EB * 8, 256, 0, stream>>>(src, dst, cnt, ebuf);
    gemm64h<<<GB, 256, 0, stream>>>(x, W1, cnt, dinv, invd, xw, N_NODES);
    agg_gemm_relu<<<AB, 256, 0, stream>>>(xw, cnt, ebuf, dinv, invd, b1, W2, y2);
    agg_pool<<<AB, 256, 0, stream>>>(y2, cnt, ebuf, dinv, invd, b2, Wout, batch, outsum);
    finalize<<<(NUM_GRAPHS + 255) / 256, 256, 0, stream>>>(outsum, batch, bout, out);
}

// Round 9
// 268.525 us; speedup vs baseline: 1.7003x; 1.0262x over previous
//
#include <hip/hip_runtime.h>
#include <hip/hip_bf16.h>
#include <hip/hip_fp16.h>

#define N_NODES   100000
#define N_EDGES   1000000
#define HID       64
#define NUM_GRAPHS 1024
#define NREP      8    // outsum atomic replicas
#define CAP       64   // max in-degree bucket capacity (Poisson(10): max deg ~30)

typedef _Float16 h16;

static __device__ __forceinline__ int pack2(float a, float b) {
    union { h16 h[2]; int i; } u;
    u.h[0] = (h16)a; u.h[1] = (h16)b;
    return u.i;
}
static __device__ __forceinline__ float uni_f(float x) {
    return __int_as_float(__builtin_amdgcn_readfirstlane(__float_as_int(x)));
}

// ---------------- graph build: XCD-partitioned bucket fill ----------------
// Partition p owns dst granules where (d>>7)&7 == p; blockIdx&7 ~ XCD id.
// Keeps each partition's 3.2MB write set in one XCD L2 (R8: 60->~12MB writes).

__global__ __launch_bounds__(256) void bucket_fill(const int* __restrict__ src,
                                                   const int* __restrict__ dst,
                                                   int* __restrict__ cnt,
                                                   int* __restrict__ ebuf) {
    int part  = blockIdx.x & 7;
    int e     = (blockIdx.x >> 3) * 256 + threadIdx.x;
    if (e >= N_EDGES) return;
    int d = dst[e];
    if (((d >> 7) & 7) != part) return;
    int p = atomicAdd(&cnt[d], 1);
    if (p < CAP) ebuf[(size_t)d * CAP + p] = src[e];
}

// ---------------- XW' = (X @ W1) * dinv, fp16 out, fused node_prep --------
// 2 threads per row (32 channels each). Pre-scaling by dinv[row] makes the
// aggregation edge-term norm-free: agg_i = dinv_i * (XW'_i + sum XW'_src).

__global__ __launch_bounds__(256) void gemm64h(const float* __restrict__ X,
                                               const float* __restrict__ W,
                                               const int* __restrict__ cnt,
                                               float* __restrict__ dinv,
                                               h16* __restrict__ Y, int nrows) {
    __shared__ float Wl[4096];
    int t = threadIdx.x;
    #pragma unroll
    for (int i = 0; i < 4; i++) {
        int idx = (t + i * 256) * 4;
        *(float4*)(Wl + idx) = *(const float4*)(W + idx);
    }
    __syncthreads();
    int row  = blockIdx.x * 128 + (t >> 1);
    if (row >= nrows) return;
    int half = t & 1;   // which 32 channels

    float df = (float)(min(cnt[row], CAP) + 1);   // +1 self loop
    float sc = rsqrtf(df);
    if (half == 0) dinv[row] = sc;

    const float4* xr = (const float4*)(X + (size_t)row * 64);
    float4 acc[8];
    #pragma unroll
    for (int j = 0; j < 8; j++) acc[j] = make_float4(0.f, 0.f, 0.f, 0.f);
    const float* wb = Wl + half * 32;
    #pragma unroll
    for (int k4 = 0; k4 < 16; k4++) {
        float4 xv = xr[k4];
        #pragma unroll
        for (int kk = 0; kk < 4; kk++) {
            float xk = (kk == 0) ? xv.x : (kk == 1) ? xv.y : (kk == 2) ? xv.z : xv.w;
            const float4* wr = (const float4*)(wb + (k4 * 4 + kk) * 64);
            #pragma unroll
            for (int j = 0; j < 8; j++) {
                float4 w = wr[j];
                acc[j].x += xk * w.x;
                acc[j].y += xk * w.y;
                acc[j].z += xk * w.z;
                acc[j].w += xk * w.w;
            }
        }
    }
    int4* yr = (int4*)(Y + (size_t)row * 64 + half * 32);
    #pragma unroll
    for (int j = 0; j < 4; j++) {
        float4 a = acc[2 * j], b = acc[2 * j + 1];
        int4 o;
        o.x = pack2(a.x * sc, a.y * sc); o.y = pack2(a.z * sc, a.w * sc);
        o.z = pack2(b.x * sc, b.y * sc); o.w = pack2(b.z * sc, b.w * sc);
        yr[j] = o;
    }
}

// ---------------- aggregation: one wave per node, lane = channel ----------------
// Inputs pre-scaled by dinv[src] -> per-edge work: readlane(src) + load + cvt
// + add. Gathers in unmasked chunks (16 + binary tail) for MLP.

template <int U>
static __device__ __forceinline__ float agg_chunk(const h16* __restrict__ XW,
                                                  int es, int j, int lane) {
    int ss[U]; float vv[U];
    #pragma unroll
    for (int u = 0; u < U; u++) ss[u] = __builtin_amdgcn_readlane(es, j + u);
    #pragma unroll
    for (int u = 0; u < U; u++)
        vv[u] = (float)XW[(((unsigned)ss[u]) << 6) | (unsigned)lane];
    float a = 0.f;
    #pragma unroll
    for (int u = 0; u < U; u++) a += vv[u];
    return a;
}

static __device__ __forceinline__ float agg_edges(const h16* __restrict__ XW,
                                                  const int* __restrict__ ebuf,
                                                  int wid, int deg, int lane) {
    if (deg <= 0) return 0.f;
    int es = ebuf[wid * CAP + (lane < deg ? lane : deg - 1)];
    float acc = 0.f;
    int j = 0;
    for (; j + 16 <= deg; j += 16) { acc += agg_chunk<16>(XW, es, j, lane); }
    if (deg & 8) { acc += agg_chunk<8>(XW, es, j, lane); j += 8; }
    if (deg & 4) { acc += agg_chunk<4>(XW, es, j, lane); j += 4; }
    if (deg & 2) { acc += agg_chunk<2>(XW, es, j, lane); j += 2; }
    if (deg & 1) { acc += agg_chunk<1>(XW, es, j, lane); }
    return acc;
}

// layer-1 agg + bias + ReLU + fused (h @ W2)*dinv -> Y2' (fp16).
// GEMV via LDS: h-row broadcast in b128 quads, W2 k-quad-interleaved.
// Per 4 k: 2 ds_read_b128 + 4 fmac (~96 issue slots/node vs 192 readlane ver).
__global__ __launch_bounds__(256) void agg_gemm_relu(const h16* __restrict__ XW,
                                                     const int* __restrict__ cnt,
                                                     const int* __restrict__ ebuf,
                                                     const float* __restrict__ dinv,
                                                     const float* __restrict__ bias,
                                                     const float* __restrict__ W2,
                                                     h16* __restrict__ Y2) {
    __shared__ float W2q[4096];   // W2q[(k>>2)*256 + c*4 + (k&3)]
    __shared__ float hbuf[256];   // 4 waves x 64
    int t = threadIdx.x;
    #pragma unroll
    for (int i = 0; i < 16; i++) {
        int L = t + i * 256;            // L = k*64 + c
        int k = L >> 6, c = L & 63;
        W2q[(k >> 2) * 256 + c * 4 + (k & 3)] = W2[L];
    }
    __syncthreads();

    int lane = t & 63;
    int w = t >> 6;
    int wid = __builtin_amdgcn_readfirstlane(blockIdx.x * 4 + w);
    float h = 0.f;
    float dvw = 0.f;
    if (wid < N_NODES) {
        int deg = min(__builtin_amdgcn_readfirstlane(cnt[wid]), CAP);
        dvw = uni_f(dinv[wid]);
        float acc = (float)XW[(((unsigned)wid) << 6) | (unsigned)lane];
        acc += agg_edges(XW, ebuf, wid, deg, lane);
        h = fmaxf(fmaf(dvw, acc, bias[lane]), 0.f);
    }
    hbuf[t] = h;
    __syncthreads();
    if (wid >= N_NODES) return;

    float y = 0.f;
    const float* hb = hbuf + w * 64;
    #pragma unroll
    for (int k4 = 0; k4 < 16; k4++) {
        float4 hp = *(const float4*)(hb + k4 * 4);              // broadcast
        float4 wq = *(const float4*)(W2q + k4 * 256 + lane * 4);
        y = fmaf(hp.x, wq.x, y);
        y = fmaf(hp.y, wq.y, y);
        y = fmaf(hp.z, wq.z, y);
        y = fmaf(hp.w, wq.w, y);
    }
    Y2[(((unsigned)wid) << 6) | (unsigned)lane] = (h16)(y * dvw);
}

// layer-2 aggregation + ReLU + dot(Wout) + per-graph accumulation
__global__ __launch_bounds__(256) void agg_pool(const h16* __restrict__ XW,
                                                const int* __restrict__ cnt,
                                                const int* __restrict__ ebuf,
                                                const float* __restrict__ dinv,
                                                const float* __restrict__ bias,
                                                const float* __restrict__ Wout,
                                                const int* __restrict__ batch,
                                                float* __restrict__ outsum) {
    int lane = threadIdx.x & 63;
    int wid = __builtin_amdgcn_readfirstlane(blockIdx.x * 4 + (threadIdx.x >> 6));
    if (wid >= N_NODES) return;
    int deg = min(__builtin_amdgcn_readfirstlane(cnt[wid]), CAP);
    float dvw = uni_f(dinv[wid]);
    float acc = (float)XW[(((unsigned)wid) << 6) | (unsigned)lane];
    acc += agg_edges(XW, ebuf, wid, deg, lane);
    float h = fmaxf(fmaf(dvw, acc, bias[lane]), 0.f);
    float v = h * Wout[lane];
    #pragma unroll
    for (int off = 32; off > 0; off >>= 1) v += __shfl_down(v, off, 64);
    if (lane == 0) {
        int g = batch[wid];
        atomicAdd(&outsum[(wid & (NREP - 1)) * NUM_GRAPHS + g], v);
    }
}

__global__ __launch_bounds__(256) void finalize(const float* __restrict__ outsum,
                                                const int* __restrict__ batch,
                                                const float* __restrict__ bout,
                                                float* __restrict__ out) {
    int g = blockIdx.x * 256 + threadIdx.x;
    if (g >= NUM_GRAPHS) return;
    float s = 0.f;
    #pragma unroll
    for (int r = 0; r < NREP; r++) s += outsum[r * NUM_GRAPHS + g];
    int lo = 0, hi = N_NODES;
    while (lo < hi) { int mid = (lo + hi) >> 1; if (batch[mid] <  g) lo = mid + 1; else hi = mid; }
    int lo2 = lo, hi2 = N_NODES;
    while (lo2 < hi2) { int mid = (lo2 + hi2) >> 1; if (batch[mid] <= g) lo2 = mid + 1; else hi2 = mid; }
    float c = (float)max(lo2 - lo, 1);
    out[g] = s / c + bout[0];
}

// ---------------- launch ----------------

extern "C" void kernel_launch(void* const* d_in, const int* in_sizes, int n_in,
                              void* d_out, int out_size, void* d_ws, size_t ws_size,
                              hipStream_t stream) {
    const float* x     = (const float*)d_in[0];
    const int*   eidx  = (const int*)d_in[1];   // [2, E]
    const int*   batch = (const int*)d_in[2];
    const float* W1    = (const float*)d_in[3];
    const float* b1    = (const float*)d_in[4];
    const float* W2    = (const float*)d_in[5];
    const float* b2    = (const float*)d_in[6];
    const float* Wout  = (const float*)d_in[7];
    const float* bout  = (const float*)d_in[8];
    float* out = (float*)d_out;

    const int* src = eidx;
    const int* dst = eidx + N_EDGES;

    // workspace layout
    h16*   xw     = (h16*)d_ws;                         // 12.8 MB
    h16*   y2     = xw + (size_t)N_NODES * 64;          // 12.8 MB
    int*   ebuf   = (int*)(y2 + (size_t)N_NODES * 64);  // 25.6 MB
    int*   cnt    = ebuf + (size_t)N_NODES * CAP;       // 400 KB
    float* outsum = (float*)(cnt + N_NODES);            // 32 KB
    float* dinv   = outsum + NREP * NUM_GRAPHS;         // 400 KB

    // zero cnt + outsum (contiguous)
    hipMemsetAsync(cnt, 0, (size_t)(N_NODES + NREP * NUM_GRAPHS) * sizeof(int), stream);

    const int EB = (N_EDGES + 255) / 256;
    const int GB = (N_NODES + 127) / 128;   // 2 threads per row
    const int AB = (N_NODES + 3) / 4;       // 4 nodes (waves) per block

    bucket_fill<<<EB * 8, 256, 0, stream>>>(src, dst, cnt, ebuf);
    gemm64h<<<GB, 256, 0, stream>>>(x, W1, cnt, dinv, xw, N_NODES);
    agg_gemm_relu<<<AB, 256, 0, stream>>>(xw, cnt, ebuf, dinv, b1, W2, y2);
    agg_pool<<<AB, 256, 0, stream>>>(y2, cnt, ebuf, dinv, b2, Wout, batch, outsum);
    finalize<<<(NUM_GRAPHS + 255) / 256, 256, 0, stream>>>(outsum, batch, bout, out);
}

// Round 10
// 254.659 us; speedup vs baseline: 1.7929x; 1.0545x over previous
//
#include <hip/hip_runtime.h>
#include <hip/hip_bf16.h>
#include <hip/hip_fp16.h>

#define N_NODES   100000
#define N_EDGES   1000000
#define HID       64
#define NUM_GRAPHS 1024
#define NREP      8    // outsum atomic replicas
#define CAP       64   // max in-degree bucket capacity (Poisson(10): max deg ~30)
#define NITER     16   // node-groups per block in agg_gemm_relu (64 nodes/block)

typedef _Float16 h16;

static __device__ __forceinline__ int pack2(float a, float b) {
    union { h16 h[2]; int i; } u;
    u.h[0] = (h16)a; u.h[1] = (h16)b;
    return u.i;
}
static __device__ __forceinline__ float uni_f(float x) {
    return __int_as_float(__builtin_amdgcn_readfirstlane(__float_as_int(x)));
}

// ---------------- graph build: XCD-partitioned bucket fill ----------------
// Partition p owns dst granules where (d>>7)&7 == p; blockIdx&7 ~ XCD id.
// Keeps each partition's 3.2MB write set in one XCD L2 (R8: 60->~12MB writes).

__global__ __launch_bounds__(256) void bucket_fill(const int* __restrict__ src,
                                                   const int* __restrict__ dst,
                                                   int* __restrict__ cnt,
                                                   int* __restrict__ ebuf) {
    int part  = blockIdx.x & 7;
    int e     = (blockIdx.x >> 3) * 256 + threadIdx.x;
    if (e >= N_EDGES) return;
    int d = dst[e];
    if (((d >> 7) & 7) != part) return;
    int p = atomicAdd(&cnt[d], 1);
    if (p < CAP) ebuf[(size_t)d * CAP + p] = src[e];
}

// ---------------- XW' = (X @ W1) * dinv, fp16 out, fused node_prep --------
// 2 threads per row (32 channels each). Pre-scaling by dinv[row] makes the
// aggregation edge-term norm-free: agg_i = dinv_i * (XW'_i + sum XW'_src).

__global__ __launch_bounds__(256) void gemm64h(const float* __restrict__ X,
                                               const float* __restrict__ W,
                                               const int* __restrict__ cnt,
                                               float* __restrict__ dinv,
                                               h16* __restrict__ Y, int nrows) {
    __shared__ float Wl[4096];
    int t = threadIdx.x;
    #pragma unroll
    for (int i = 0; i < 4; i++) {
        int idx = (t + i * 256) * 4;
        *(float4*)(Wl + idx) = *(const float4*)(W + idx);
    }
    __syncthreads();
    int row  = blockIdx.x * 128 + (t >> 1);
    if (row >= nrows) return;
    int half = t & 1;   // which 32 channels

    float df = (float)(min(cnt[row], CAP) + 1);   // +1 self loop
    float sc = rsqrtf(df);
    if (half == 0) dinv[row] = sc;

    const float4* xr = (const float4*)(X + (size_t)row * 64);
    float4 acc[8];
    #pragma unroll
    for (int j = 0; j < 8; j++) acc[j] = make_float4(0.f, 0.f, 0.f, 0.f);
    const float* wb = Wl + half * 32;
    #pragma unroll
    for (int k4 = 0; k4 < 16; k4++) {
        float4 xv = xr[k4];
        #pragma unroll
        for (int kk = 0; kk < 4; kk++) {
            float xk = (kk == 0) ? xv.x : (kk == 1) ? xv.y : (kk == 2) ? xv.z : xv.w;
            const float4* wr = (const float4*)(wb + (k4 * 4 + kk) * 64);
            #pragma unroll
            for (int j = 0; j < 8; j++) {
                float4 w = wr[j];
                acc[j].x += xk * w.x;
                acc[j].y += xk * w.y;
                acc[j].z += xk * w.z;
                acc[j].w += xk * w.w;
            }
        }
    }
    int4* yr = (int4*)(Y + (size_t)row * 64 + half * 32);
    #pragma unroll
    for (int j = 0; j < 4; j++) {
        float4 a = acc[2 * j], b = acc[2 * j + 1];
        int4 o;
        o.x = pack2(a.x * sc, a.y * sc); o.y = pack2(a.z * sc, a.w * sc);
        o.z = pack2(b.x * sc, b.y * sc); o.w = pack2(b.z * sc, b.w * sc);
        yr[j] = o;
    }
}

// ---------------- aggregation: one wave per node, lane = channel ----------------
// Inputs pre-scaled by dinv[src] -> per-edge work: readlane(src) + load + cvt
// + add. Gathers in unmasked chunks (16 + binary tail) for MLP.

template <int U>
static __device__ __forceinline__ float agg_chunk(const h16* __restrict__ XW,
                                                  int es, int j, int lane) {
    int ss[U]; float vv[U];
    #pragma unroll
    for (int u = 0; u < U; u++) ss[u] = __builtin_amdgcn_readlane(es, j + u);
    #pragma unroll
    for (int u = 0; u < U; u++)
        vv[u] = (float)XW[(((unsigned)ss[u]) << 6) | (unsigned)lane];
    float a = 0.f;
    #pragma unroll
    for (int u = 0; u < U; u++) a += vv[u];
    return a;
}

static __device__ __forceinline__ float agg_edges(const h16* __restrict__ XW,
                                                  const int* __restrict__ ebuf,
                                                  int wid, int deg, int lane) {
    if (deg <= 0) return 0.f;
    int es = ebuf[wid * CAP + (lane < deg ? lane : deg - 1)];
    float acc = 0.f;
    int j = 0;
    for (; j + 16 <= deg; j += 16) { acc += agg_chunk<16>(XW, es, j, lane); }
    if (deg & 8) { acc += agg_chunk<8>(XW, es, j, lane); j += 8; }
    if (deg & 4) { acc += agg_chunk<4>(XW, es, j, lane); j += 4; }
    if (deg & 2) { acc += agg_chunk<2>(XW, es, j, lane); j += 2; }
    if (deg & 1) { acc += agg_chunk<1>(XW, es, j, lane); }
    return acc;
}

// layer-1 agg + bias + ReLU + fused (h @ W2)*dinv -> Y2' (fp16).
// Block processes NITER*4 = 64 nodes; W2 staged ONCE per block (R9 staged
// 16KB per 4 nodes -> dominated issue slots + 8-way-conflict LDS writes).
// hbuf slices are wave-private -> no per-iteration __syncthreads needed.
__global__ __launch_bounds__(256) void agg_gemm_relu(const h16* __restrict__ XW,
                                                     const int* __restrict__ cnt,
                                                     const int* __restrict__ ebuf,
                                                     const float* __restrict__ dinv,
                                                     const float* __restrict__ bias,
                                                     const float* __restrict__ W2,
                                                     h16* __restrict__ Y2) {
    __shared__ float W2q[4096];   // W2q[(k>>2)*256 + c*4 + (k&3)]
    __shared__ float hbuf[256];   // 4 waves x 64, wave-private slices
    int t = threadIdx.x;
    #pragma unroll
    for (int i = 0; i < 16; i++) {
        int L = t + i * 256;            // L = k*64 + c
        int k = L >> 6, c = L & 63;
        W2q[(k >> 2) * 256 + c * 4 + (k & 3)] = W2[L];
    }
    __syncthreads();

    int lane = t & 63;
    int w = t >> 6;
    float* hb = hbuf + w * 64;
    float bl = bias[lane];

    for (int it = 0; it < NITER; it++) {
        int wid = __builtin_amdgcn_readfirstlane(
            (blockIdx.x * NITER + it) * 4 + w);
        if (wid >= N_NODES) return;
        int deg = min(__builtin_amdgcn_readfirstlane(cnt[wid]), CAP);
        float dvw = uni_f(dinv[wid]);
        float acc = (float)XW[(((unsigned)wid) << 6) | (unsigned)lane];
        acc += agg_edges(XW, ebuf, wid, deg, lane);
        float h = fmaxf(fmaf(dvw, acc, bl), 0.f);

        hb[lane] = h;   // wave-private: only intra-wave lgkmcnt ordering needed
        float y = 0.f;
        #pragma unroll
        for (int k4 = 0; k4 < 16; k4++) {
            float4 hp = *(const float4*)(hb + k4 * 4);              // broadcast
            float4 wq = *(const float4*)(W2q + k4 * 256 + lane * 4);
            y = fmaf(hp.x, wq.x, y);
            y = fmaf(hp.y, wq.y, y);
            y = fmaf(hp.z, wq.z, y);
            y = fmaf(hp.w, wq.w, y);
        }
        Y2[(((unsigned)wid) << 6) | (unsigned)lane] = (h16)(y * dvw);
    }
}

// layer-2 aggregation + ReLU + dot(Wout) + per-graph accumulation
__global__ __launch_bounds__(256) void agg_pool(const h16* __restrict__ XW,
                                                const int* __restrict__ cnt,
                                                const int* __restrict__ ebuf,
                                                const float* __restrict__ dinv,
                                                const float* __restrict__ bias,
                                                const float* __restrict__ Wout,
                                                const int* __restrict__ batch,
                                                float* __restrict__ outsum) {
    int lane = threadIdx.x & 63;
    int wid = __builtin_amdgcn_readfirstlane(blockIdx.x * 4 + (threadIdx.x >> 6));
    if (wid >= N_NODES) return;
    int deg = min(__builtin_amdgcn_readfirstlane(cnt[wid]), CAP);
    float dvw = uni_f(dinv[wid]);
    float acc = (float)XW[(((unsigned)wid) << 6) | (unsigned)lane];
    acc += agg_edges(XW, ebuf, wid, deg, lane);
    float h = fmaxf(fmaf(dvw, acc, bias[lane]), 0.f);
    float v = h * Wout[lane];
    #pragma unroll
    for (int off = 32; off > 0; off >>= 1) v += __shfl_down(v, off, 64);
    if (lane == 0) {
        int g = batch[wid];
        atomicAdd(&outsum[(wid & (NREP - 1)) * NUM_GRAPHS + g], v);
    }
}

__global__ __launch_bounds__(256) void finalize(const float* __restrict__ outsum,
                                                const int* __restrict__ batch,
                                                const float* __restrict__ bout,
                                                float* __restrict__ out) {
    int g = blockIdx.x * 256 + threadIdx.x;
    if (g >= NUM_GRAPHS) return;
    float s = 0.f;
    #pragma unroll
    for (int r = 0; r < NREP; r++) s += outsum[r * NUM_GRAPHS + g];
    int lo = 0, hi = N_NODES;
    while (lo < hi) { int mid = (lo + hi) >> 1; if (batch[mid] <  g) lo = mid + 1; else hi = mid; }
    int lo2 = lo, hi2 = N_NODES;
    while (lo2 < hi2) { int mid = (lo2 + hi2) >> 1; if (batch[mid] <= g) lo2 = mid + 1; else hi2 = mid; }
    float c = (float)max(lo2 - lo, 1);
    out[g] = s / c + bout[0];
}

// ---------------- launch ----------------

extern "C" void kernel_launch(void* const* d_in, const int* in_sizes, int n_in,
                              void* d_out, int out_size, void* d_ws, size_t ws_size,
                              hipStream_t stream) {
    const float* x     = (const float*)d_in[0];
    const int*   eidx  = (const int*)d_in[1];   // [2, E]
    const int*   batch = (const int*)d_in[2];
    const float* W1    = (const float*)d_in[3];
    const float* b1    = (const float*)d_in[4];
    const float* W2    = (const float*)d_in[5];
    const float* b2    = (const float*)d_in[6];
    const float* Wout  = (const float*)d_in[7];
    const float* bout  = (const float*)d_in[8];
    float* out = (float*)d_out;

    const int* src = eidx;
    const int* dst = eidx + N_EDGES;

    // workspace layout
    h16*   xw     = (h16*)d_ws;                         // 12.8 MB
    h16*   y2     = xw + (size_t)N_NODES * 64;          // 12.8 MB
    int*   ebuf   = (int*)(y2 + (size_t)N_NODES * 64);  // 25.6 MB
    int*   cnt    = ebuf + (size_t)N_NODES * CAP;       // 400 KB
    float* outsum = (float*)(cnt + N_NODES);            // 32 KB
    float* dinv   = outsum + NREP * NUM_GRAPHS;         // 400 KB

    // zero cnt + outsum (contiguous)
    hipMemsetAsync(cnt, 0, (size_t)(N_NODES + NREP * NUM_GRAPHS) * sizeof(int), stream);

    const int EB = (N_EDGES + 255) / 256;
    const int GB = (N_NODES + 127) / 128;                  // 2 threads per row
    const int AB = (N_NODES + 3) / 4;                      // agg_pool: 4 nodes/block
    const int FB = (N_NODES + NITER * 4 - 1) / (NITER * 4); // agg_gemm: 64 nodes/block

    bucket_fill<<<EB * 8, 256, 0, stream>>>(src, dst, cnt, ebuf);
    gemm64h<<<GB, 256, 0, stream>>>(x, W1, cnt, dinv, xw, N_NODES);
    agg_gemm_relu<<<FB, 256, 0, stream>>>(xw, cnt, ebuf, dinv, b1, W2, y2);
    agg_pool<<<AB, 256, 0, stream>>>(y2, cnt, ebuf, dinv, b2, Wout, batch, outsum);
    finalize<<<(NUM_GRAPHS + 255) / 256, 256, 0, stream>>>(outsum, batch, bout, out);
}